// Round 9
// baseline (260.485 us; speedup 1.0000x reference)
//
#include <hip/hip_runtime.h>
#include <hip/hip_bf16.h>
#include <stdint.h>

// Attention_65214783422545: B=4, S=1024, D=1024, H=16, dk=64
// outputs: attn_w [4,16,1024,1024] fp32 then y [4,1024,1024] fp32
//
// Workspace layout (48 MB):
//   0   : xb   bf16 [4096][1024]            8 MB
//   8M  : wqkv bf16 [3072][1024]            6 MB   (Wq | Wk | Wv)
//   14M : wob  bf16 [1024][1024]            2 MB
//   16M : qbp  bf16 [64][1024][64] (scaled) 8 MB
//   24M : kbp  bf16 [64][1024][64]          8 MB
//   32M : vTb  bf16 [64][64][1024]          8 MB
//   40M : yh   bf16 [4096][1024]            8 MB

typedef short short8 __attribute__((ext_vector_type(8)));
typedef short short4v __attribute__((ext_vector_type(4)));
typedef float f32x4 __attribute__((ext_vector_type(4)));

__device__ __forceinline__ short f2bf(float f) {
    union { __hip_bfloat16 h; short s; } u;
    u.h = __float2bfloat16(f);
    return u.s;
}
__device__ __forceinline__ float bf2f(short s) {
    union { uint32_t u; float f; } c;
    c.u = ((uint32_t)(uint16_t)s) << 16;
    return c.f;
}

#define GLD16(g, l) __builtin_amdgcn_global_load_lds( \
    (const __attribute__((address_space(1))) void*)(g), \
    (__attribute__((address_space(3))) void*)(l), 16, 0, 0)

// ---------------- cast all fp32 inputs -> bf16, one launch ----------------
// seg 0..3: Wq,Wk,Wv,Wo (262144 float4 each); seg 4..7: quarter of x each.
__global__ __launch_bounds__(256) void castall_kernel(const float* __restrict__ x,
                                                      const float* __restrict__ w0,
                                                      const float* __restrict__ w1,
                                                      const float* __restrict__ w2,
                                                      const float* __restrict__ w3,
                                                      short* __restrict__ xb,
                                                      short* __restrict__ qkv,
                                                      short* __restrict__ wo) {
    const int seg = blockIdx.y;
    const float* src;
    short* dst;
    if (seg < 4) {
        src = seg == 0 ? w0 : seg == 1 ? w1 : seg == 2 ? w2 : w3;
        dst = seg < 3 ? qkv + (size_t)seg * 1048576 : wo;
    } else {
        src = x + (size_t)(seg - 4) * 1048576;
        dst = xb + (size_t)(seg - 4) * 1048576;
    }
    for (int i = blockIdx.x * 256 + threadIdx.x; i < 262144; i += gridDim.x * 256) {
        float4 v = ((const float4*)src)[i];
        short4v o;
        o[0] = f2bf(v.x); o[1] = f2bf(v.y); o[2] = f2bf(v.z); o[3] = f2bf(v.w);
        ((short4v*)dst)[i] = o;
    }
}

// ---------------- GEMM: C[M,N] = A[M,K] @ B[N,K]^T + bias ----------------
// Double-buffered LDS (T3 minimum 2-phase): stage tile t+1 before computing
// tile t; single barrier per iter. m97-class overlap of HBM latency w/ MFMA.
// mode 4: fused QKV (N=3072); seg = tN>>10 routes to Q (scaled, [B,H,S,64]),
//         K ([B,H,S,64]), V (transposed, [B,H,64,S]); bias per segment.
// mode 3: O-proj, fp32 out [M][1024] + bias b0.
__global__ __launch_bounds__(256) void gemm_bt(const short* __restrict__ A,
                                               const short* __restrict__ Bw,
                                               const float* __restrict__ b0,
                                               const float* __restrict__ b1,
                                               const float* __restrict__ b2,
                                               short* __restrict__ outq,
                                               short* __restrict__ outk,
                                               short* __restrict__ outv,
                                               float* __restrict__ fout,
                                               int mode) {
    __shared__ __align__(16) short As[2][128 * 32];
    __shared__ __align__(16) short Bs[2][128 * 32];

    const int tid = threadIdx.x;
    const int wave = tid >> 6, lane = tid & 63;
    const int l15 = lane & 15, l4 = lane >> 4;
    const int wm = wave >> 1, wn = wave & 1;
    const int tM = blockIdx.y * 128, tN = blockIdx.x * 128;

    f32x4 acc[4][4] = {};

    auto stage = [&](int buf, int kt) {
        #pragma unroll
        for (int rep = 0; rep < 2; ++rep) {
            int slot = (wave * 2 + rep) * 64 + lane;
            int e0 = slot * 8;
            int row = e0 >> 5, col = e0 & 31;
            GLD16(&A[(size_t)(tM + row) * 1024 + kt + col],
                  (char*)&As[buf][0] + (size_t)(wave * 2 + rep) * 1024);
            GLD16(&Bw[(size_t)(tN + row) * 1024 + kt + col],
                  (char*)&Bs[buf][0] + (size_t)(wave * 2 + rep) * 1024);
        }
    };

    stage(0, 0);
    __syncthreads();          // tile 0 landed
    int cur = 0;

    for (int t = 0; t < 32; ++t) {
        if (t < 31) stage(cur ^ 1, (t + 1) * 32);   // async prefetch next tile

        short8 af[4], bfr[4];
        #pragma unroll
        for (int f = 0; f < 4; ++f) {
            af[f]  = *(const short8*)&As[cur][(wm * 64 + f * 16 + l15) * 32 + l4 * 8];
            bfr[f] = *(const short8*)&Bs[cur][(wn * 64 + f * 16 + l15) * 32 + l4 * 8];
        }
        #pragma unroll
        for (int i = 0; i < 4; ++i)
            #pragma unroll
            for (int j = 0; j < 4; ++j)
                acc[i][j] = __builtin_amdgcn_mfma_f32_16x16x32_bf16(af[i], bfr[j], acc[i][j], 0, 0, 0);

        __syncthreads();      // drains prefetch; readers done with buf cur
        cur ^= 1;
    }

    const int seg = tN >> 10;  // block-uniform (mode 4)
    const float* bias = (mode == 3) ? b0 : (seg == 0 ? b0 : seg == 1 ? b1 : b2);

    #pragma unroll
    for (int i = 0; i < 4; ++i) {
        #pragma unroll
        for (int j = 0; j < 4; ++j) {
            #pragma unroll
            for (int v = 0; v < 4; ++v) {
                int gr = tM + wm * 64 + i * 16 + l4 * 4 + v;  // m
                int gc = tN + wn * 64 + j * 16 + l15;         // n
                if (mode == 3) {
                    fout[(size_t)gr * 1024 + gc] = acc[i][j][v] + bias[gc];
                } else {
                    int nloc = gc & 1023;
                    float val = acc[i][j][v] + bias[nloc];
                    int bb = gr >> 10, s = gr & 1023, h = nloc >> 6, dk = nloc & 63;
                    if (seg == 0) {
                        outq[(((size_t)bb * 16 + h) * 1024 + s) * 64 + dk] = f2bf(val * 0.125f);
                    } else if (seg == 1) {
                        outk[(((size_t)bb * 16 + h) * 1024 + s) * 64 + dk] = f2bf(val);
                    } else {
                        outv[(((size_t)bb * 16 + h) * 64 + dk) * 1024 + s] = f2bf(val);
                    }
                }
            }
        }
    }
}

// ---------------- fused attention ----------------
// grid: (x=bh 64, y=ip 16), block 512 (8 waves = 2 row-groups x 4 col-groups).
// Each block processes TWO qb tiles: qb = 31-ip (heavy) then qb = ip (light).
// Per-block work is constant (perfect balance); light half's K/V is a subset
// of heavy half's -> L2-resident on second pass (fetch ~= heavy extent only).
// Scores sc[16] in registers (static indices only, rule #20). attn_w stored
// fp32 directly from registers after normalize (drains under PV).
__global__ __launch_bounds__(512, 4) void attn_kernel(const short* __restrict__ q,
                                                      const short* __restrict__ k,
                                                      const short* __restrict__ vT,
                                                      float* __restrict__ attn,
                                                      short* __restrict__ yh) {
    const int bh = blockIdx.x;
    const int ip = blockIdx.y;           // 0..15
    const int tid = threadIdx.x;
    const int wave = tid >> 6, lane = tid & 63;
    const int l15 = lane & 15, l4 = lane >> 4;
    const int rg = wave & 1, cg = wave >> 1;
    const int c0w = cg * 256;            // this wave's first col

    __shared__ __align__(16) short pb[32][1032];   // 66 KB, pad +8
    __shared__ float mred[4][32];
    __shared__ float sred[4][32];

    const int b = bh >> 4, h = bh & 15;

    for (int half = 0; half < 2; ++half) {
        const int qb = half == 0 ? (31 - ip) : ip;   // heavy first
        const int q0 = qb * 32;
        const int rbase = q0 + rg * 16;

        // Q fragments for rows rbase..rbase+15
        short8 qf[2];
        {
            const short* qrow = q + ((size_t)bh * 1024 + rbase + l15) * 64;
            qf[0] = *(const short8*)(qrow + l4 * 8);
            qf[1] = *(const short8*)(qrow + 32 + l4 * 8);
        }

        // ---- scores: fully unrolled, static sc indices; wave-uniform guard ----
        f32x4 sc[16] = {};
        #pragma unroll
        for (int cf = 0; cf < 16; ++cf) {
            if (c0w + cf * 16 < rbase + 16) {
                const short* krow = k + ((size_t)bh * 1024 + c0w + cf * 16 + l15) * 64;
                short8 kf0 = *(const short8*)(krow + l4 * 8);
                short8 kf1 = *(const short8*)(krow + 32 + l4 * 8);
                sc[cf] = __builtin_amdgcn_mfma_f32_16x16x32_bf16(qf[0], kf0, sc[cf], 0, 0, 0);
                sc[cf] = __builtin_amdgcn_mfma_f32_16x16x32_bf16(qf[1], kf1, sc[cf], 0, 0, 0);
            }
        }

        // ---- row max ----
        float mrow[4];
        #pragma unroll
        for (int j = 0; j < 4; ++j) {
            int rglob = rbase + l4 * 4 + j;
            float m = -1e30f;
            #pragma unroll
            for (int cf = 0; cf < 16; ++cf) {
                int col = c0w + cf * 16 + l15;
                m = fmaxf(m, (col <= rglob) ? sc[cf][j] : -1e30f);
            }
            m = fmaxf(m, __shfl_xor(m, 1));
            m = fmaxf(m, __shfl_xor(m, 2));
            m = fmaxf(m, __shfl_xor(m, 4));
            m = fmaxf(m, __shfl_xor(m, 8));
            mrow[j] = m;
        }
        if (l15 == 0) {
            #pragma unroll
            for (int j = 0; j < 4; ++j) mred[cg][rg * 16 + l4 * 4 + j] = mrow[j];
        }
        __syncthreads();
        #pragma unroll
        for (int j = 0; j < 4; ++j) {
            int r = rg * 16 + l4 * 4 + j;
            mrow[j] = fmaxf(fmaxf(mred[0][r], mred[1][r]), fmaxf(mred[2][r], mred[3][r]));
        }

        // ---- exp + row sum ----
        float inv[4], ls[4];
        #pragma unroll
        for (int j = 0; j < 4; ++j) {
            int rglob = rbase + l4 * 4 + j;
            float s = 0.f;
            #pragma unroll
            for (int cf = 0; cf < 16; ++cf) {
                int col = c0w + cf * 16 + l15;
                float e = (col <= rglob) ? __expf(sc[cf][j] - mrow[j]) : 0.f;
                sc[cf][j] = e;
                s += e;
            }
            s += __shfl_xor(s, 1);
            s += __shfl_xor(s, 2);
            s += __shfl_xor(s, 4);
            s += __shfl_xor(s, 8);
            ls[j] = s;
        }
        if (l15 == 0) {
            #pragma unroll
            for (int j = 0; j < 4; ++j) sred[cg][rg * 16 + l4 * 4 + j] = ls[j];
        }
        __syncthreads();
        #pragma unroll
        for (int j = 0; j < 4; ++j) {
            int r = rg * 16 + l4 * 4 + j;
            inv[j] = 1.0f / (sred[0][r] + sred[1][r] + sred[2][r] + sred[3][r]);
        }

        // ---- direct fp32 attn_w stores (post early; drain under PV) ----
        {
            float* abase = attn + (size_t)bh * 1048576;
            #pragma unroll
            for (int j = 0; j < 4; ++j) {
                float* arow = abase + (size_t)(rbase + l4 * 4 + j) * 1024 + l15;
                float iv = inv[j];
                #pragma unroll
                for (int cf = 0; cf < 16; ++cf) {
                    arow[c0w + cf * 16] = sc[cf][j] * iv;   // masked entries exact 0
                }
            }
        }

        // ---- pb (bf16): only cols PV will read (col < q0+64) ----
        #pragma unroll
        for (int cf = 0; cf < 16; ++cf) {
            if (c0w + cf * 16 < q0 + 64) {
                #pragma unroll
                for (int j = 0; j < 4; ++j) {
                    pb[rg * 16 + l4 * 4 + j][c0w + cf * 16 + l15] = f2bf(sc[cf][j] * inv[j]);
                }
            }
        }
        __syncthreads();

        // ---- PV: wave (rg,cg) -> Y rows rg*16, dk cols cg*16; causal trim ----
        f32x4 yacc = {};
        {
            const short* vrow = vT + ((size_t)bh * 64 + cg * 16 + l15) * 1024;
            const int nch = (rbase + 16 + 31) >> 5;
            for (int ks = 0; ks < nch; ++ks) {
                short8 pf = *(const short8*)&pb[rg * 16 + l15][ks * 32 + l4 * 8];
                short8 vf = *(const short8*)(vrow + ks * 32 + l4 * 8);
                yacc = __builtin_amdgcn_mfma_f32_16x16x32_bf16(pf, vf, yacc, 0, 0, 0);
            }
        }

        // ---- write y_heads ----
        #pragma unroll
        for (int j = 0; j < 4; ++j) {
            yh[((size_t)b * 1024 + rbase + l4 * 4 + j) * 1024 + h * 64 + cg * 16 + l15] = f2bf(yacc[j]);
        }

        __syncthreads();   // pb/mred/sred safe for next half
    }
}

extern "C" void kernel_launch(void* const* d_in, const int* in_sizes, int n_in,
                              void* d_out, int out_size, void* d_ws, size_t ws_size,
                              hipStream_t stream) {
    const float* x  = (const float*)d_in[0];
    const float* Wq = (const float*)d_in[1];
    const float* bq = (const float*)d_in[2];
    const float* Wk = (const float*)d_in[3];
    const float* bk = (const float*)d_in[4];
    const float* Wv = (const float*)d_in[5];
    const float* bv = (const float*)d_in[6];
    const float* Wo = (const float*)d_in[7];
    const float* bo = (const float*)d_in[8];

    char* ws = (char*)d_ws;
    short* xb   = (short*)(ws + ((size_t)0 << 20));
    short* wqkv = (short*)(ws + ((size_t)8 << 20));
    short* wob  = (short*)(ws + ((size_t)14 << 20));
    short* qbp  = (short*)(ws + ((size_t)16 << 20));
    short* kbp  = (short*)(ws + ((size_t)24 << 20));
    short* vTb  = (short*)(ws + ((size_t)32 << 20));
    short* yh   = (short*)(ws + ((size_t)40 << 20));

    float* attn = (float*)d_out;
    float* yout = attn + (size_t)67108864;

    castall_kernel<<<dim3(128, 8), 256, 0, stream>>>(x, Wq, Wk, Wv, Wo, xb, wqkv, wob);

    gemm_bt<<<dim3(24, 32), 256, 0, stream>>>(xb, wqkv, bq, bk, bv, qbp, kbp, vTb, nullptr, 4);

    attn_kernel<<<dim3(64, 16), 512, 0, stream>>>(qbp, kbp, vTb, attn, yh);

    gemm_bt<<<dim3(8, 32), 256, 0, stream>>>(yh, wob, bo, bo, bo, nullptr, nullptr, nullptr, yout, 3);
}

// Round 10
// 230.821 us; speedup vs baseline: 1.1285x; 1.1285x over previous
//
#include <hip/hip_runtime.h>
#include <hip/hip_bf16.h>
#include <stdint.h>

// Attention_65214783422545: B=4, S=1024, D=1024, H=16, dk=64
// outputs: attn_w [4,16,1024,1024] fp32 then y [4,1024,1024] fp32
//
// Workspace layout (48 MB):
//   0   : xb   bf16 [4096][1024]            8 MB
//   8M  : wqkv bf16 [3072][1024]            6 MB   (Wq | Wk | Wv)
//   14M : wob  bf16 [1024][1024]            2 MB
//   16M : qbp  bf16 [64][1024][64] (scaled) 8 MB
//   24M : kbp  bf16 [64][1024][64]          8 MB
//   32M : vTb  bf16 [64][64][1024]          8 MB
//   40M : yh   bf16 [4096][1024]            8 MB

typedef short short8 __attribute__((ext_vector_type(8)));
typedef short short4v __attribute__((ext_vector_type(4)));
typedef float f32x4 __attribute__((ext_vector_type(4)));

__device__ __forceinline__ short f2bf(float f) {
    union { __hip_bfloat16 h; short s; } u;
    u.h = __float2bfloat16(f);
    return u.s;
}
__device__ __forceinline__ float bf2f(short s) {
    union { uint32_t u; float f; } c;
    c.u = ((uint32_t)(uint16_t)s) << 16;
    return c.f;
}

#define GLD16(g, l) __builtin_amdgcn_global_load_lds( \
    (const __attribute__((address_space(1))) void*)(g), \
    (__attribute__((address_space(3))) void*)(l), 16, 0, 0)

// ---------------- cast all fp32 inputs -> bf16, one launch ----------------
// seg 0..3: Wq,Wk,Wv,Wo (262144 float4 each); seg 4..7: quarter of x each.
__global__ __launch_bounds__(256) void castall_kernel(const float* __restrict__ x,
                                                      const float* __restrict__ w0,
                                                      const float* __restrict__ w1,
                                                      const float* __restrict__ w2,
                                                      const float* __restrict__ w3,
                                                      short* __restrict__ xb,
                                                      short* __restrict__ qkv,
                                                      short* __restrict__ wo) {
    const int seg = blockIdx.y;
    const float* src;
    short* dst;
    if (seg < 4) {
        src = seg == 0 ? w0 : seg == 1 ? w1 : seg == 2 ? w2 : w3;
        dst = seg < 3 ? qkv + (size_t)seg * 1048576 : wo;
    } else {
        src = x + (size_t)(seg - 4) * 1048576;
        dst = xb + (size_t)(seg - 4) * 1048576;
    }
    for (int i = blockIdx.x * 256 + threadIdx.x; i < 262144; i += gridDim.x * 256) {
        float4 v = ((const float4*)src)[i];
        short4v o;
        o[0] = f2bf(v.x); o[1] = f2bf(v.y); o[2] = f2bf(v.z); o[3] = f2bf(v.w);
        ((short4v*)dst)[i] = o;
    }
}

// ---------------- GEMM: C[M,N] = A[M,K] @ B[N,K]^T + bias ----------------
// (round-8 structure: single-buffer stage -> barrier -> MFMA -> barrier)
// mode 4: fused QKV (N=3072); seg = tN>>10 routes to Q (scaled, [B,H,S,64]),
//         K ([B,H,S,64]), V (transposed, [B,H,64,S]); bias per segment.
// mode 3: O-proj, fp32 out [M][1024] + bias b0.
__global__ __launch_bounds__(256) void gemm_bt(const short* __restrict__ A,
                                               const short* __restrict__ Bw,
                                               const float* __restrict__ b0,
                                               const float* __restrict__ b1,
                                               const float* __restrict__ b2,
                                               short* __restrict__ outq,
                                               short* __restrict__ outk,
                                               short* __restrict__ outv,
                                               float* __restrict__ fout,
                                               int mode) {
    __shared__ __align__(16) short As[128 * 32];
    __shared__ __align__(16) short Bs[128 * 32];

    const int tid = threadIdx.x;
    const int wave = tid >> 6, lane = tid & 63;
    const int l15 = lane & 15, l4 = lane >> 4;
    const int wm = wave >> 1, wn = wave & 1;
    const int tM = blockIdx.y * 128, tN = blockIdx.x * 128;

    f32x4 acc[4][4] = {};

    for (int kt = 0; kt < 1024; kt += 32) {
        #pragma unroll
        for (int rep = 0; rep < 2; ++rep) {
            int slot = (wave * 2 + rep) * 64 + lane;
            int e0 = slot * 8;
            int row = e0 >> 5, col = e0 & 31;
            GLD16(&A[(size_t)(tM + row) * 1024 + kt + col], (char*)As + (size_t)(wave * 2 + rep) * 1024);
            GLD16(&Bw[(size_t)(tN + row) * 1024 + kt + col], (char*)Bs + (size_t)(wave * 2 + rep) * 1024);
        }
        __syncthreads();

        short8 af[4], bfr[4];
        #pragma unroll
        for (int f = 0; f < 4; ++f) {
            af[f]  = *(const short8*)&As[(wm * 64 + f * 16 + l15) * 32 + l4 * 8];
            bfr[f] = *(const short8*)&Bs[(wn * 64 + f * 16 + l15) * 32 + l4 * 8];
        }
        #pragma unroll
        for (int i = 0; i < 4; ++i)
            #pragma unroll
            for (int j = 0; j < 4; ++j)
                acc[i][j] = __builtin_amdgcn_mfma_f32_16x16x32_bf16(af[i], bfr[j], acc[i][j], 0, 0, 0);
        __syncthreads();
    }

    const int seg = tN >> 10;  // block-uniform (mode 4)
    const float* bias = (mode == 3) ? b0 : (seg == 0 ? b0 : seg == 1 ? b1 : b2);

    #pragma unroll
    for (int i = 0; i < 4; ++i) {
        #pragma unroll
        for (int j = 0; j < 4; ++j) {
            #pragma unroll
            for (int v = 0; v < 4; ++v) {
                int gr = tM + wm * 64 + i * 16 + l4 * 4 + v;  // m
                int gc = tN + wn * 64 + j * 16 + l15;         // n
                if (mode == 3) {
                    fout[(size_t)gr * 1024 + gc] = acc[i][j][v] + bias[gc];
                } else {
                    int nloc = gc & 1023;
                    float val = acc[i][j][v] + bias[nloc];
                    int bb = gr >> 10, s = gr & 1023, h = nloc >> 6, dk = nloc & 63;
                    if (seg == 0) {
                        outq[(((size_t)bb * 16 + h) * 1024 + s) * 64 + dk] = f2bf(val * 0.125f);
                    } else if (seg == 1) {
                        outk[(((size_t)bb * 16 + h) * 1024 + s) * 64 + dk] = f2bf(val);
                    } else {
                        outv[(((size_t)bb * 16 + h) * 64 + dk) * 1024 + s] = f2bf(val);
                    }
                }
            }
        }
    }
}

// ---------------- fused attention ----------------
// grid: (x=bh 64, y=32), block 512 (8 waves = 2 row-groups x 4 col-groups).
// qb = (y&1) ? 31-(y>>1) : (y>>1): adjacent y alternate light/heavy so every
// resident cohort (8 y-values) is work-balanced; concurrent heavy blocks'
// K/V fetches are a superset the light blocks hit in L2.
// Body identical to round 8: sc[16] in registers (static indices, rule #20);
// attn_w stored fp32 directly after normalize (drains under PV); pb trimmed.
__global__ __launch_bounds__(512, 4) void attn_kernel(const short* __restrict__ q,
                                                      const short* __restrict__ k,
                                                      const short* __restrict__ vT,
                                                      float* __restrict__ attn,
                                                      short* __restrict__ yh) {
    const int bh = blockIdx.x;
    const int y = blockIdx.y;
    const int qb = (y & 1) ? (31 - (y >> 1)) : (y >> 1);
    const int tid = threadIdx.x;
    const int wave = tid >> 6, lane = tid & 63;
    const int l15 = lane & 15, l4 = lane >> 4;
    const int rg = wave & 1, cg = wave >> 1;
    const int q0 = qb * 32;
    const int rbase = q0 + rg * 16;      // this wave's first global q-row
    const int c0w = cg * 256;            // this wave's first col

    __shared__ __align__(16) short pb[32][1032];   // 66 KB, pad +8
    __shared__ float mred[4][32];
    __shared__ float sred[4][32];

    // Q fragments for rows rbase..rbase+15
    short8 qf[2];
    {
        const short* qrow = q + ((size_t)bh * 1024 + rbase + l15) * 64;
        qf[0] = *(const short8*)(qrow + l4 * 8);
        qf[1] = *(const short8*)(qrow + 32 + l4 * 8);
    }

    // ---- scores: fully unrolled, static sc indices; wave-uniform guard ----
    f32x4 sc[16] = {};
    #pragma unroll
    for (int cf = 0; cf < 16; ++cf) {
        if (c0w + cf * 16 < rbase + 16) {   // wave-uniform runtime condition
            const short* krow = k + ((size_t)bh * 1024 + c0w + cf * 16 + l15) * 64;
            short8 kf0 = *(const short8*)(krow + l4 * 8);
            short8 kf1 = *(const short8*)(krow + 32 + l4 * 8);
            sc[cf] = __builtin_amdgcn_mfma_f32_16x16x32_bf16(qf[0], kf0, sc[cf], 0, 0, 0);
            sc[cf] = __builtin_amdgcn_mfma_f32_16x16x32_bf16(qf[1], kf1, sc[cf], 0, 0, 0);
        }
    }

    // ---- row max ----
    float mrow[4];
    #pragma unroll
    for (int j = 0; j < 4; ++j) {
        int rglob = rbase + l4 * 4 + j;
        float m = -1e30f;
        #pragma unroll
        for (int cf = 0; cf < 16; ++cf) {
            int col = c0w + cf * 16 + l15;
            m = fmaxf(m, (col <= rglob) ? sc[cf][j] : -1e30f);
        }
        m = fmaxf(m, __shfl_xor(m, 1));
        m = fmaxf(m, __shfl_xor(m, 2));
        m = fmaxf(m, __shfl_xor(m, 4));
        m = fmaxf(m, __shfl_xor(m, 8));
        mrow[j] = m;
    }
    if (l15 == 0) {
        #pragma unroll
        for (int j = 0; j < 4; ++j) mred[cg][rg * 16 + l4 * 4 + j] = mrow[j];
    }
    __syncthreads();
    #pragma unroll
    for (int j = 0; j < 4; ++j) {
        int r = rg * 16 + l4 * 4 + j;
        mrow[j] = fmaxf(fmaxf(mred[0][r], mred[1][r]), fmaxf(mred[2][r], mred[3][r]));
    }

    // ---- exp + row sum ----
    float inv[4], ls[4];
    #pragma unroll
    for (int j = 0; j < 4; ++j) {
        int rglob = rbase + l4 * 4 + j;
        float s = 0.f;
        #pragma unroll
        for (int cf = 0; cf < 16; ++cf) {
            int col = c0w + cf * 16 + l15;
            float e = (col <= rglob) ? __expf(sc[cf][j] - mrow[j]) : 0.f;
            sc[cf][j] = e;
            s += e;
        }
        s += __shfl_xor(s, 1);
        s += __shfl_xor(s, 2);
        s += __shfl_xor(s, 4);
        s += __shfl_xor(s, 8);
        ls[j] = s;
    }
    if (l15 == 0) {
        #pragma unroll
        for (int j = 0; j < 4; ++j) sred[cg][rg * 16 + l4 * 4 + j] = ls[j];
    }
    __syncthreads();
    #pragma unroll
    for (int j = 0; j < 4; ++j) {
        int r = rg * 16 + l4 * 4 + j;
        inv[j] = 1.0f / (sred[0][r] + sred[1][r] + sred[2][r] + sred[3][r]);
    }

    // ---- direct fp32 attn_w stores (post early; drain under PV) ----
    {
        float* abase = attn + (size_t)bh * 1048576;
        #pragma unroll
        for (int j = 0; j < 4; ++j) {
            float* arow = abase + (size_t)(rbase + l4 * 4 + j) * 1024 + l15;
            float iv = inv[j];
            #pragma unroll
            for (int cf = 0; cf < 16; ++cf) {
                arow[c0w + cf * 16] = sc[cf][j] * iv;   // masked entries exact 0
            }
        }
    }

    // ---- pb (bf16): only cols PV will read (col < q0+64) ----
    #pragma unroll
    for (int cf = 0; cf < 16; ++cf) {
        if (c0w + cf * 16 < q0 + 64) {   // wave-uniform
            #pragma unroll
            for (int j = 0; j < 4; ++j) {
                pb[rg * 16 + l4 * 4 + j][c0w + cf * 16 + l15] = f2bf(sc[cf][j] * inv[j]);
            }
        }
    }
    __syncthreads();

    // ---- PV: wave (rg,cg) -> Y rows rg*16, dk cols cg*16; trim to causal ----
    f32x4 yacc = {};
    {
        const short* vrow = vT + ((size_t)bh * 64 + cg * 16 + l15) * 1024;
        const int nch = (rbase + 16 + 31) >> 5;   // cols beyond rbase+16 are 0
        for (int ks = 0; ks < nch; ++ks) {
            short8 pf = *(const short8*)&pb[rg * 16 + l15][ks * 32 + l4 * 8];
            short8 vf = *(const short8*)(vrow + ks * 32 + l4 * 8);
            yacc = __builtin_amdgcn_mfma_f32_16x16x32_bf16(pf, vf, yacc, 0, 0, 0);
        }
    }

    // ---- write y_heads ----
    const int b = bh >> 4, h = bh & 15;
    #pragma unroll
    for (int j = 0; j < 4; ++j) {
        yh[((size_t)b * 1024 + rbase + l4 * 4 + j) * 1024 + h * 64 + cg * 16 + l15] = f2bf(yacc[j]);
    }
}

extern "C" void kernel_launch(void* const* d_in, const int* in_sizes, int n_in,
                              void* d_out, int out_size, void* d_ws, size_t ws_size,
                              hipStream_t stream) {
    const float* x  = (const float*)d_in[0];
    const float* Wq = (const float*)d_in[1];
    const float* bq = (const float*)d_in[2];
    const float* Wk = (const float*)d_in[3];
    const float* bk = (const float*)d_in[4];
    const float* Wv = (const float*)d_in[5];
    const float* bv = (const float*)d_in[6];
    const float* Wo = (const float*)d_in[7];
    const float* bo = (const float*)d_in[8];

    char* ws = (char*)d_ws;
    short* xb   = (short*)(ws + ((size_t)0 << 20));
    short* wqkv = (short*)(ws + ((size_t)8 << 20));
    short* wob  = (short*)(ws + ((size_t)14 << 20));
    short* qbp  = (short*)(ws + ((size_t)16 << 20));
    short* kbp  = (short*)(ws + ((size_t)24 << 20));
    short* vTb  = (short*)(ws + ((size_t)32 << 20));
    short* yh   = (short*)(ws + ((size_t)40 << 20));

    float* attn = (float*)d_out;
    float* yout = attn + (size_t)67108864;

    castall_kernel<<<dim3(128, 8), 256, 0, stream>>>(x, Wq, Wk, Wv, Wo, xb, wqkv, wob);

    gemm_bt<<<dim3(24, 32), 256, 0, stream>>>(xb, wqkv, bq, bk, bv, qbp, kbp, vTb, nullptr, 4);

    attn_kernel<<<dim3(64, 32), 512, 0, stream>>>(qbp, kbp, vTb, attn, yh);

    gemm_bt<<<dim3(8, 32), 256, 0, stream>>>(yh, wob, bo, bo, bo, nullptr, nullptr, nullptr, yout, 3);
}

// Round 11
// 200.981 us; speedup vs baseline: 1.2961x; 1.1485x over previous
//
#include <hip/hip_runtime.h>
#include <hip/hip_bf16.h>
#include <stdint.h>

// Attention_65214783422545: B=4, S=1024, D=1024, H=16, dk=64
// outputs: attn_w [4,16,1024,1024] fp32 then y [4,1024,1024] fp32
//
// Workspace layout (48 MB):
//   0   : xb   bf16 [4096][1024]            8 MB
//   8M  : wqkv bf16 [3072][1024]            6 MB   (Wq | Wk | Wv)
//   14M : wob  bf16 [1024][1024]            2 MB
//   16M : qbp  bf16 [64][1024][64] (scaled) 8 MB
//   24M : kbp  bf16 [64][1024][64]          8 MB
//   32M : vTb  bf16 [64][64][1024]          8 MB
//   40M : yh   bf16 [4096][1024]            8 MB

typedef short short8 __attribute__((ext_vector_type(8)));
typedef short short4v __attribute__((ext_vector_type(4)));
typedef float f32x4 __attribute__((ext_vector_type(4)));

__device__ __forceinline__ short f2bf(float f) {
    union { __hip_bfloat16 h; short s; } u;
    u.h = __float2bfloat16(f);
    return u.s;
}
__device__ __forceinline__ float bf2f(short s) {
    union { uint32_t u; float f; } c;
    c.u = ((uint32_t)(uint16_t)s) << 16;
    return c.f;
}

#define GLD16(g, l) __builtin_amdgcn_global_load_lds( \
    (const __attribute__((address_space(1))) void*)(g), \
    (__attribute__((address_space(3))) void*)(l), 16, 0, 0)

// ---------------- cast all fp32 inputs -> bf16, one launch ----------------
// seg 0..3: Wq,Wk,Wv,Wo (262144 float4 each); seg 4..7: quarter of x each.
__global__ __launch_bounds__(256) void castall_kernel(const float* __restrict__ x,
                                                      const float* __restrict__ w0,
                                                      const float* __restrict__ w1,
                                                      const float* __restrict__ w2,
                                                      const float* __restrict__ w3,
                                                      short* __restrict__ xb,
                                                      short* __restrict__ qkv,
                                                      short* __restrict__ wo) {
    const int seg = blockIdx.y;
    const float* src;
    short* dst;
    if (seg < 4) {
        src = seg == 0 ? w0 : seg == 1 ? w1 : seg == 2 ? w2 : w3;
        dst = seg < 3 ? qkv + (size_t)seg * 1048576 : wo;
    } else {
        src = x + (size_t)(seg - 4) * 1048576;
        dst = xb + (size_t)(seg - 4) * 1048576;
    }
    for (int i = blockIdx.x * 256 + threadIdx.x; i < 262144; i += gridDim.x * 256) {
        float4 v = ((const float4*)src)[i];
        short4v o;
        o[0] = f2bf(v.x); o[1] = f2bf(v.y); o[2] = f2bf(v.z); o[3] = f2bf(v.w);
        ((short4v*)dst)[i] = o;
    }
}

// ---------------- GEMM: C[M,N] = A[M,K] @ B[N,K]^T + bias ----------------
// T3 minimum 2-phase double-buffer: stage tile t+1 into buf^1 BEFORE the MFMAs
// of tile t; single barrier per iter drains the prefetch. (A/B vs round-10's
// stage->barrier->compute which exposes full HBM latency each iter.)
// mode 4: fused QKV (N=3072); seg = tN>>10 routes to Q (scaled, [B,H,S,64]),
//         K ([B,H,S,64]), V (transposed, [B,H,64,S], packed 8B stores).
// mode 3: O-proj, fp32 out [M][1024] + bias b0.
__global__ __launch_bounds__(256) void gemm_bt(const short* __restrict__ A,
                                               const short* __restrict__ Bw,
                                               const float* __restrict__ b0,
                                               const float* __restrict__ b1,
                                               const float* __restrict__ b2,
                                               short* __restrict__ outq,
                                               short* __restrict__ outk,
                                               short* __restrict__ outv,
                                               float* __restrict__ fout,
                                               int mode) {
    __shared__ __align__(16) short As[2][128 * 32];
    __shared__ __align__(16) short Bs[2][128 * 32];

    const int tid = threadIdx.x;
    const int wave = tid >> 6, lane = tid & 63;
    const int l15 = lane & 15, l4 = lane >> 4;
    const int wm = wave >> 1, wn = wave & 1;
    const int tM = blockIdx.y * 128, tN = blockIdx.x * 128;

    f32x4 acc[4][4] = {};

    auto stage = [&](int buf, int kt) {
        #pragma unroll
        for (int rep = 0; rep < 2; ++rep) {
            int slot = (wave * 2 + rep) * 64 + lane;
            int e0 = slot * 8;
            int row = e0 >> 5, col = e0 & 31;
            GLD16(&A[(size_t)(tM + row) * 1024 + kt + col],
                  (char*)&As[buf][0] + (size_t)(wave * 2 + rep) * 1024);
            GLD16(&Bw[(size_t)(tN + row) * 1024 + kt + col],
                  (char*)&Bs[buf][0] + (size_t)(wave * 2 + rep) * 1024);
        }
    };

    stage(0, 0);
    __syncthreads();
    int cur = 0;

    for (int t = 0; t < 32; ++t) {
        if (t < 31) stage(cur ^ 1, (t + 1) * 32);

        short8 af[4], bfr[4];
        #pragma unroll
        for (int f = 0; f < 4; ++f) {
            af[f]  = *(const short8*)&As[cur][(wm * 64 + f * 16 + l15) * 32 + l4 * 8];
            bfr[f] = *(const short8*)&Bs[cur][(wn * 64 + f * 16 + l15) * 32 + l4 * 8];
        }
        #pragma unroll
        for (int i = 0; i < 4; ++i)
            #pragma unroll
            for (int j = 0; j < 4; ++j)
                acc[i][j] = __builtin_amdgcn_mfma_f32_16x16x32_bf16(af[i], bfr[j], acc[i][j], 0, 0, 0);

        __syncthreads();   // prefetch landed; readers done with buf cur
        cur ^= 1;
    }

    const int seg = tN >> 10;  // block-uniform (mode 4)
    const float* bias = (mode == 3) ? b0 : (seg == 0 ? b0 : seg == 1 ? b1 : b2);

    #pragma unroll
    for (int i = 0; i < 4; ++i) {
        #pragma unroll
        for (int j = 0; j < 4; ++j) {
            if (mode == 4 && seg == 2) {
                // V: vT[(b*16+h)*64+dk][s]; 4 v-values = 4 consecutive s -> one 8B store
                int gr0 = tM + wm * 64 + i * 16 + l4 * 4;
                int gc  = tN + wn * 64 + j * 16 + l15;
                int nloc = gc & 1023;
                int bb = gr0 >> 10, s0 = gr0 & 1023, h = nloc >> 6, dk = nloc & 63;
                float bv_ = bias[nloc];
                short4v pk;
                #pragma unroll
                for (int v = 0; v < 4; ++v) pk[v] = f2bf(acc[i][j][v] + bv_);
                *(short4v*)&outv[(((size_t)bb * 16 + h) * 64 + dk) * 1024 + s0] = pk;
            } else {
                #pragma unroll
                for (int v = 0; v < 4; ++v) {
                    int gr = tM + wm * 64 + i * 16 + l4 * 4 + v;  // m
                    int gc = tN + wn * 64 + j * 16 + l15;         // n
                    if (mode == 3) {
                        fout[(size_t)gr * 1024 + gc] = acc[i][j][v] + bias[gc];
                    } else {
                        int nloc = gc & 1023;
                        float val = acc[i][j][v] + bias[nloc];
                        int bb = gr >> 10, s = gr & 1023, h = nloc >> 6, dk = nloc & 63;
                        if (seg == 0) {
                            outq[(((size_t)bb * 16 + h) * 1024 + s) * 64 + dk] = f2bf(val * 0.125f);
                        } else {
                            outk[(((size_t)bb * 16 + h) * 1024 + s) * 64 + dk] = f2bf(val);
                        }
                    }
                }
            }
        }
    }
}

// ---------------- fused attention (byte-identical to round-10 baseline) ----
__global__ __launch_bounds__(512, 4) void attn_kernel(const short* __restrict__ q,
                                                      const short* __restrict__ k,
                                                      const short* __restrict__ vT,
                                                      float* __restrict__ attn,
                                                      short* __restrict__ yh) {
    const int bh = blockIdx.x;
    const int y = blockIdx.y;
    const int qb = (y & 1) ? (31 - (y >> 1)) : (y >> 1);
    const int tid = threadIdx.x;
    const int wave = tid >> 6, lane = tid & 63;
    const int l15 = lane & 15, l4 = lane >> 4;
    const int rg = wave & 1, cg = wave >> 1;
    const int q0 = qb * 32;
    const int rbase = q0 + rg * 16;
    const int c0w = cg * 256;

    __shared__ __align__(16) short pb[32][1032];
    __shared__ float mred[4][32];
    __shared__ float sred[4][32];

    short8 qf[2];
    {
        const short* qrow = q + ((size_t)bh * 1024 + rbase + l15) * 64;
        qf[0] = *(const short8*)(qrow + l4 * 8);
        qf[1] = *(const short8*)(qrow + 32 + l4 * 8);
    }

    f32x4 sc[16] = {};
    #pragma unroll
    for (int cf = 0; cf < 16; ++cf) {
        if (c0w + cf * 16 < rbase + 16) {
            const short* krow = k + ((size_t)bh * 1024 + c0w + cf * 16 + l15) * 64;
            short8 kf0 = *(const short8*)(krow + l4 * 8);
            short8 kf1 = *(const short8*)(krow + 32 + l4 * 8);
            sc[cf] = __builtin_amdgcn_mfma_f32_16x16x32_bf16(qf[0], kf0, sc[cf], 0, 0, 0);
            sc[cf] = __builtin_amdgcn_mfma_f32_16x16x32_bf16(qf[1], kf1, sc[cf], 0, 0, 0);
        }
    }

    float mrow[4];
    #pragma unroll
    for (int j = 0; j < 4; ++j) {
        int rglob = rbase + l4 * 4 + j;
        float m = -1e30f;
        #pragma unroll
        for (int cf = 0; cf < 16; ++cf) {
            int col = c0w + cf * 16 + l15;
            m = fmaxf(m, (col <= rglob) ? sc[cf][j] : -1e30f);
        }
        m = fmaxf(m, __shfl_xor(m, 1));
        m = fmaxf(m, __shfl_xor(m, 2));
        m = fmaxf(m, __shfl_xor(m, 4));
        m = fmaxf(m, __shfl_xor(m, 8));
        mrow[j] = m;
    }
    if (l15 == 0) {
        #pragma unroll
        for (int j = 0; j < 4; ++j) mred[cg][rg * 16 + l4 * 4 + j] = mrow[j];
    }
    __syncthreads();
    #pragma unroll
    for (int j = 0; j < 4; ++j) {
        int r = rg * 16 + l4 * 4 + j;
        mrow[j] = fmaxf(fmaxf(mred[0][r], mred[1][r]), fmaxf(mred[2][r], mred[3][r]));
    }

    float inv[4], ls[4];
    #pragma unroll
    for (int j = 0; j < 4; ++j) {
        int rglob = rbase + l4 * 4 + j;
        float s = 0.f;
        #pragma unroll
        for (int cf = 0; cf < 16; ++cf) {
            int col = c0w + cf * 16 + l15;
            float e = (col <= rglob) ? __expf(sc[cf][j] - mrow[j]) : 0.f;
            sc[cf][j] = e;
            s += e;
        }
        s += __shfl_xor(s, 1);
        s += __shfl_xor(s, 2);
        s += __shfl_xor(s, 4);
        s += __shfl_xor(s, 8);
        ls[j] = s;
    }
    if (l15 == 0) {
        #pragma unroll
        for (int j = 0; j < 4; ++j) sred[cg][rg * 16 + l4 * 4 + j] = ls[j];
    }
    __syncthreads();
    #pragma unroll
    for (int j = 0; j < 4; ++j) {
        int r = rg * 16 + l4 * 4 + j;
        inv[j] = 1.0f / (sred[0][r] + sred[1][r] + sred[2][r] + sred[3][r]);
    }

    {
        float* abase = attn + (size_t)bh * 1048576;
        #pragma unroll
        for (int j = 0; j < 4; ++j) {
            float* arow = abase + (size_t)(rbase + l4 * 4 + j) * 1024 + l15;
            float iv = inv[j];
            #pragma unroll
            for (int cf = 0; cf < 16; ++cf) {
                arow[c0w + cf * 16] = sc[cf][j] * iv;
            }
        }
    }

    #pragma unroll
    for (int cf = 0; cf < 16; ++cf) {
        if (c0w + cf * 16 < q0 + 64) {
            #pragma unroll
            for (int j = 0; j < 4; ++j) {
                pb[rg * 16 + l4 * 4 + j][c0w + cf * 16 + l15] = f2bf(sc[cf][j] * inv[j]);
            }
        }
    }
    __syncthreads();

    f32x4 yacc = {};
    {
        const short* vrow = vT + ((size_t)bh * 64 + cg * 16 + l15) * 1024;
        const int nch = (rbase + 16 + 31) >> 5;
        for (int ks = 0; ks < nch; ++ks) {
            short8 pf = *(const short8*)&pb[rg * 16 + l15][ks * 32 + l4 * 8];
            short8 vf = *(const short8*)(vrow + ks * 32 + l4 * 8);
            yacc = __builtin_amdgcn_mfma_f32_16x16x32_bf16(pf, vf, yacc, 0, 0, 0);
        }
    }

    const int b = bh >> 4, h = bh & 15;
    #pragma unroll
    for (int j = 0; j < 4; ++j) {
        yh[((size_t)b * 1024 + rbase + l4 * 4 + j) * 1024 + h * 64 + cg * 16 + l15] = f2bf(yacc[j]);
    }
}

extern "C" void kernel_launch(void* const* d_in, const int* in_sizes, int n_in,
                              void* d_out, int out_size, void* d_ws, size_t ws_size,
                              hipStream_t stream) {
    const float* x  = (const float*)d_in[0];
    const float* Wq = (const float*)d_in[1];
    const float* bq = (const float*)d_in[2];
    const float* Wk = (const float*)d_in[3];
    const float* bk = (const float*)d_in[4];
    const float* Wv = (const float*)d_in[5];
    const float* bv = (const float*)d_in[6];
    const float* Wo = (const float*)d_in[7];
    const float* bo = (const float*)d_in[8];

    char* ws = (char*)d_ws;
    short* xb   = (short*)(ws + ((size_t)0 << 20));
    short* wqkv = (short*)(ws + ((size_t)8 << 20));
    short* wob  = (short*)(ws + ((size_t)14 << 20));
    short* qbp  = (short*)(ws + ((size_t)16 << 20));
    short* kbp  = (short*)(ws + ((size_t)24 << 20));
    short* vTb  = (short*)(ws + ((size_t)32 << 20));
    short* yh   = (short*)(ws + ((size_t)40 << 20));

    float* attn = (float*)d_out;
    float* yout = attn + (size_t)67108864;

    castall_kernel<<<dim3(128, 8), 256, 0, stream>>>(x, Wq, Wk, Wv, Wo, xb, wqkv, wob);

    gemm_bt<<<dim3(24, 32), 256, 0, stream>>>(xb, wqkv, bq, bk, bv, qbp, kbp, vTb, nullptr, 4);

    attn_kernel<<<dim3(64, 32), 512, 0, stream>>>(qbp, kbp, vTb, attn, yh);

    gemm_bt<<<dim3(8, 32), 256, 0, stream>>>(yh, wob, bo, bo, bo, nullptr, nullptr, nullptr, yout, 3);
}